// Round 1
// baseline (80.720 us; speedup 1.0000x reference)
//
#include <hip/hip_runtime.h>
#include <hip/hip_cooperative_groups.h>
#include <math.h>

namespace cg = cooperative_groups;

// Problem constants (from reference)
#define POOLD 50
#define GFD   45
#define DNND  400
#define ZIN   (POOLD + GFD)   // 95

// Parallel decomposition: 25 wgs x 16 output columns = 400 outputs/layer.
// Threads: t = kt*16 + tt ; tt = output lane (coalesced 64B rows), kt = K-split.
#define NWG 25
#define TT  16
#define KT  16
#define BLK (TT * KT)         // 256

__device__ __forceinline__ float elu1(float x) {
    return x > 0.f ? x : expm1f(x);
}

// The entire GNN front-end is analytically dead:
//   global_mean_pool(BatchNorm_trainstats(h)) == bnpool_b  (exactly)
// so the output reduces to a tiny MLP on constants + gf1.
// Version 2: the MLP's 4 MB of weights was being streamed through ONE CU
// (~135 GB/s per-CU L2 ceiling -> ~30us floor). Distribute each layer's
// 400 outputs across 25 CUs with grid.sync() between dependent layers.
__global__ __launch_bounds__(BLK) void GATGraphModel_tail_coop(
    const float* __restrict__ gf1,        // [45]
    const float* __restrict__ bnpool_b,   // [14]
    const float* __restrict__ ugp1_W,     // [14,50]
    const float* __restrict__ ugp1_b,     // [50]
    const float* __restrict__ ugp2_W,     // [50,50]
    const float* __restrict__ ugp2_b,     // [50]
    const float* __restrict__ dnn0_W,     // [95,400]
    const float* __restrict__ dnn0_b,     // [400]
    const float* __restrict__ dnn_mid_W,  // [6,400,400]
    const float* __restrict__ dnn_mid_b,  // [6,400]
    const float* __restrict__ dnn_last_W, // [400,1]
    const float* __restrict__ dnn_last_b, // [1]
    float* __restrict__ out,              // [1]
    float* __restrict__ ws)               // >= 800 floats scratch
{
    cg::grid_group grid = cg::this_grid();

    __shared__ float zs[DNND];     // current activation vector (staged per wg)
    __shared__ float red[BLK];     // K-split reduction scratch
    __shared__ float h2[POOLD];

    const int t     = threadIdx.x;
    const int tt    = t & (TT - 1);
    const int kt    = t >> 4;
    const int tbase = blockIdx.x * TT;

    float* g0 = ws;          // ping
    float* g1 = ws + DNND;   // pong

    // ---- ugp chain, computed redundantly in EVERY wg (13 KB of reads,
    // cheaper than an extra grid sync): p0 = bnpool_b ; h2 = p0@ugp1 + b
    if (t < POOLD) {
        float acc = ugp1_b[t];
        #pragma unroll
        for (int c = 0; c < 14; ++c) acc += bnpool_b[c] * ugp1_W[c * POOLD + t];
        h2[t] = acc;
    }
    __syncthreads();
    // p = h2 @ ugp2_W + b ; z = concat(p, gf1) -> zs[0:95]
    if (t < POOLD) {
        float acc = ugp2_b[t];
        #pragma unroll 10
        for (int k = 0; k < POOLD; ++k) acc += h2[k] * ugp2_W[k * POOLD + t];
        zs[t] = acc;
    } else if (t < ZIN) {
        zs[t] = gf1[t - POOLD];
    }
    __syncthreads();

    // ---- dnn0: this wg's 16 outputs of z = elu(z95 @ dnn0_W + b) -> g0
    {
        float acc = 0.f;
        for (int k = kt; k < ZIN; k += KT)
            acc += zs[k] * dnn0_W[k * DNND + tbase + tt];
        red[t] = acc;
        __syncthreads();
        if (kt < 8) red[t] += red[t + 128];
        __syncthreads();
        if (kt < 4) red[t] += red[t + 64];
        __syncthreads();
        if (kt < 2) red[t] += red[t + 32];
        __syncthreads();
        if (kt == 0) {
            float v = red[t] + red[t + 16] + dnn0_b[tbase + tt];
            g0[tbase + tt] = elu1(v);
        }
    }
    grid.sync();

    // ---- 6 mid layers: z = elu(elu(z @ W + b)); ping-pong g0<->g1.
    // Per wg per layer: 400 x 16 x 4B = 25.6 KB of W reads (vs 640 KB before).
    const float* src = g0;
    float*       dst = g1;
    for (int i = 0; i < 6; ++i) {
        // stage full src vector into LDS
        for (int j = t; j < DNND; j += BLK) zs[j] = src[j];
        __syncthreads();

        const float* W = dnn_mid_W + (size_t)i * DNND * DNND;
        float acc = 0.f;
        for (int k = kt; k < DNND; k += KT)          // 25 iters
            acc += zs[k] * W[k * DNND + tbase + tt]; // 64B-coalesced per row
        red[t] = acc;
        __syncthreads();
        if (kt < 8) red[t] += red[t + 128];
        __syncthreads();
        if (kt < 4) red[t] += red[t + 64];
        __syncthreads();
        if (kt < 2) red[t] += red[t + 32];
        __syncthreads();
        if (kt == 0) {
            float v = red[t] + red[t + 16] + dnn_mid_b[i * DNND + tbase + tt];
            dst[tbase + tt] = elu1(elu1(v));
        }
        grid.sync();

        float* tmp = (float*)src; src = dst; dst = tmp;
    }
    // after 6 layers: src == g0 holds the final activation

    // ---- out = sigmoid(z @ dnn_last_W + b), wg 0 only (no trailing sync)
    if (blockIdx.x == 0 && t < 64) {
        float acc = 0.f;
        for (int k = t; k < DNND; k += 64) acc += src[k] * dnn_last_W[k];
        #pragma unroll
        for (int o = 32; o > 0; o >>= 1) acc += __shfl_down(acc, o, 64);
        if (t == 0) {
            float x = acc + dnn_last_b[0];
            out[0] = 1.f / (1.f + expf(-x));
        }
    }
}

extern "C" void kernel_launch(void* const* d_in, const int* in_sizes, int n_in,
                              void* d_out, int out_size, void* d_ws, size_t ws_size,
                              hipStream_t stream) {
    // setup_inputs() order:
    //  0 x, 1 edge_attr, 2 gf1, 3 bn_in_g, 4 bn_in_b,
    //  5 gat0_W, 6 gat0_asrc, 7 gat0_adst, 8 gat0_bias,
    //  9 gat_mid_W, 10 gat_mid_asrc, 11 gat_mid_adst, 12 gat_mid_bias,
    // 13 bn_mid_g, 14 bn_mid_b,
    // 15 gat_last_W, 16 gat_last_asrc, 17 gat_last_adst, 18 gat_last_bias,
    // 19 bnpool_g, 20 bnpool_b, 21 ugp1_W, 22 ugp1_b, 23 ugp2_W, 24 ugp2_b,
    // 25 dnn0_W, 26 dnn0_b, 27 dnn_mid_W, 28 dnn_mid_b, 29 dnn_last_W,
    // 30 dnn_last_b, 31 edge_index, 32 batch
    const float* gf1        = (const float*)d_in[2];
    const float* bnpool_b   = (const float*)d_in[20];
    const float* ugp1_W     = (const float*)d_in[21];
    const float* ugp1_b     = (const float*)d_in[22];
    const float* ugp2_W     = (const float*)d_in[23];
    const float* ugp2_b     = (const float*)d_in[24];
    const float* dnn0_W     = (const float*)d_in[25];
    const float* dnn0_b     = (const float*)d_in[26];
    const float* dnn_mid_W  = (const float*)d_in[27];
    const float* dnn_mid_b  = (const float*)d_in[28];
    const float* dnn_last_W = (const float*)d_in[29];
    const float* dnn_last_b = (const float*)d_in[30];
    float* out = (float*)d_out;
    float* ws  = (float*)d_ws;   // needs 2*400 floats = 3.2 KB

    void* args[] = {
        (void*)&gf1, (void*)&bnpool_b,
        (void*)&ugp1_W, (void*)&ugp1_b, (void*)&ugp2_W, (void*)&ugp2_b,
        (void*)&dnn0_W, (void*)&dnn0_b, (void*)&dnn_mid_W, (void*)&dnn_mid_b,
        (void*)&dnn_last_W, (void*)&dnn_last_b,
        (void*)&out, (void*)&ws
    };
    hipLaunchCooperativeKernel((void*)GATGraphModel_tail_coop,
                               dim3(NWG), dim3(BLK), args, 0, stream);
}

// Round 2
// 48.286 us; speedup vs baseline: 1.6717x; 1.6717x over previous
//
#include <hip/hip_runtime.h>
#include <math.h>

// Problem constants (from reference)
#define POOLD 50
#define GFD   45
#define DNND  400
#define ZIN   (POOLD + GFD)   // 95

// Parallel decomposition: 25 wgs x 16 output columns = 400 outputs/layer.
// t = kt*16 + tt ; tt = output lane (coalesced 64B rows), kt = 16-way K-split.
#define NWG 25
#define TT  16
#define KT  16
#define BLK (TT * KT)         // 256
#define NK  (DNND / KT)       // 25 k-iters per thread per mid layer

__device__ __forceinline__ float elu1(float x) {
    return x > 0.f ? x : expm1f(x);
}

// ---- minimal cross-wg barrier: monotonic per-phase counters in ws.
// No L2 flush (unlike cg::grid_group::sync, which cost ~12us/sync here).
// Data moves via agent-scope atomics (sc0/sc1: bypass non-coherent L1/L2),
// so visibility needs no cache maintenance at all.
__device__ __forceinline__ void bar_arrive(unsigned int* bar, int i) {
    __hip_atomic_fetch_add(&bar[i], 1u, __ATOMIC_RELEASE, __HIP_MEMORY_SCOPE_AGENT);
}
__device__ __forceinline__ void bar_spin(unsigned int* bar, int i) {
    while (__hip_atomic_load(&bar[i], __ATOMIC_RELAXED, __HIP_MEMORY_SCOPE_AGENT) < NWG)
        __builtin_amdgcn_s_sleep(1);
}

// The entire GNN front-end is analytically dead:
//   global_mean_pool(BatchNorm_trainstats(h)) == bnpool_b  (exactly)
// so the output reduces to a tiny MLP on constants + gf1.
// v3: 25-CU layer-parallel MLP with hand-rolled agent-atomic barrier.
// Per mid layer each thread preloads its 25 weight elems into registers
// BEFORE the barrier spin, so HBM latency hides under the wait.
__global__ __launch_bounds__(BLK) void GATGraphModel_tail_v3(
    const float* __restrict__ gf1,        // [45]
    const float* __restrict__ bnpool_b,   // [14]
    const float* __restrict__ ugp1_W,     // [14,50]
    const float* __restrict__ ugp1_b,     // [50]
    const float* __restrict__ ugp2_W,     // [50,50]
    const float* __restrict__ ugp2_b,     // [50]
    const float* __restrict__ dnn0_W,     // [95,400]
    const float* __restrict__ dnn0_b,     // [400]
    const float* __restrict__ dnn_mid_W,  // [6,400,400]
    const float* __restrict__ dnn_mid_b,  // [6,400]
    const float* __restrict__ dnn_last_W, // [400,1]
    const float* __restrict__ dnn_last_b, // [1]
    float* __restrict__ out,              // [1]
    float* __restrict__ ws)               // barrier cnts + 2x400f ping-pong
{
    __shared__ float zs[DNND];     // staged activation vector
    __shared__ float red[BLK];     // K-split reduction scratch
    __shared__ float h2[POOLD];

    const int t     = threadIdx.x;
    const int tt    = t & (TT - 1);
    const int kt    = t >> 4;
    const int tbase = blockIdx.x * TT;

    unsigned int* bar = (unsigned int*)ws;  // [0:64) uints, memset to 0 on stream
    float* g0 = ws + 64;                    // ping  (offset 256 B)
    float* g1 = ws + 64 + DNND;             // pong

    // ---- ugp chain, redundantly in every wg (13 KB of cached reads —
    // cheaper than an extra barrier): p0 = bnpool_b ; h2 = p0@ugp1 + b
    if (t < POOLD) {
        float acc = ugp1_b[t];
        #pragma unroll
        for (int c = 0; c < 14; ++c) acc += bnpool_b[c] * ugp1_W[c * POOLD + t];
        h2[t] = acc;
    }
    __syncthreads();
    // p = h2 @ ugp2_W + b ; z = concat(p, gf1) -> zs[0:95]
    if (t < POOLD) {
        float acc = ugp2_b[t];
        #pragma unroll 10
        for (int k = 0; k < POOLD; ++k) acc += h2[k] * ugp2_W[k * POOLD + t];
        zs[t] = acc;
    } else if (t < ZIN) {
        zs[t] = gf1[t - POOLD];
    }
    __syncthreads();

    // ---- dnn0: this wg's 16 outputs of elu(z95 @ dnn0_W + b) -> g0
    {
        float acc = 0.f;
        #pragma unroll
        for (int j = 0; j < 6; ++j) {
            int k = kt + j * KT;
            if (k < ZIN) acc += zs[k] * dnn0_W[k * DNND + tbase + tt];
        }
        red[t] = acc;
        __syncthreads();
        if (kt < 8) red[t] += red[t + 128];
        __syncthreads();
        if (kt < 4) red[t] += red[t + 64];
        __syncthreads();
        if (kt < 2) red[t] += red[t + 32];
        __syncthreads();
        if (kt == 0) {
            float v = red[t] + red[t + 16] + dnn0_b[tbase + tt];
            __hip_atomic_store(&g0[tbase + tt], elu1(v),
                               __ATOMIC_RELAXED, __HIP_MEMORY_SCOPE_AGENT);
        }
        __syncthreads();               // drains vmcnt -> stores at coherence pt
        if (t == 0) bar_arrive(bar, 0);
    }

    // ---- 6 mid layers: z = elu(elu(z @ W + b)); ping-pong g0<->g1
    for (int i = 0; i < 6; ++i) {
        const float* __restrict__ W = dnn_mid_W + (size_t)i * DNND * DNND;
        const float* src = (i & 1) ? g1 : g0;
        float*       dst = (i & 1) ? g0 : g1;

        // preload this thread's 25 weight elems; in flight during the spin
        float w[NK];
        #pragma unroll
        for (int j = 0; j < NK; ++j)
            w[j] = W[(kt + j * KT) * DNND + tbase + tt];

        if (t == 0) bar_spin(bar, i);
        __syncthreads();               // wg waits; weight loads keep flying

        // stage src -> zs via 8B coherent loads (200 of them, 1/thread)
        const unsigned long long* s8 = (const unsigned long long*)src;
        if (t < DNND / 2) {
            unsigned long long v = __hip_atomic_load(&s8[t],
                __ATOMIC_RELAXED, __HIP_MEMORY_SCOPE_AGENT);
            zs[2 * t]     = __uint_as_float((unsigned int)v);
            zs[2 * t + 1] = __uint_as_float((unsigned int)(v >> 32));
        }
        __syncthreads();

        float acc = 0.f;
        #pragma unroll
        for (int j = 0; j < NK; ++j) acc += zs[kt + j * KT] * w[j];
        red[t] = acc;
        __syncthreads();
        if (kt < 8) red[t] += red[t + 128];
        __syncthreads();
        if (kt < 4) red[t] += red[t + 64];
        __syncthreads();
        if (kt < 2) red[t] += red[t + 32];
        __syncthreads();
        if (kt == 0) {
            float v = red[t] + red[t + 16] + dnn_mid_b[i * DNND + tbase + tt];
            __hip_atomic_store(&dst[tbase + tt], elu1(elu1(v)),
                               __ATOMIC_RELAXED, __HIP_MEMORY_SCOPE_AGENT);
        }
        __syncthreads();
        if (t == 0) bar_arrive(bar, i + 1);
    }
    // final activation is in g0 (6 layers, even count)

    // ---- out = sigmoid(z @ dnn_last_W + b), wg 0 only
    if (blockIdx.x == 0) {
        if (t == 0) bar_spin(bar, 6);
        __syncthreads();
        const unsigned long long* s8 = (const unsigned long long*)g0;
        if (t < DNND / 2) {
            unsigned long long v = __hip_atomic_load(&s8[t],
                __ATOMIC_RELAXED, __HIP_MEMORY_SCOPE_AGENT);
            zs[2 * t]     = __uint_as_float((unsigned int)v);
            zs[2 * t + 1] = __uint_as_float((unsigned int)(v >> 32));
        }
        __syncthreads();
        if (t < 64) {
            float acc = 0.f;
            for (int k = t; k < DNND; k += 64) acc += zs[k] * dnn_last_W[k];
            #pragma unroll
            for (int o = 32; o > 0; o >>= 1) acc += __shfl_down(acc, o, 64);
            if (t == 0) {
                float x = acc + dnn_last_b[0];
                out[0] = 1.f / (1.f + expf(-x));
            }
        }
    }
}

extern "C" void kernel_launch(void* const* d_in, const int* in_sizes, int n_in,
                              void* d_out, int out_size, void* d_ws, size_t ws_size,
                              hipStream_t stream) {
    // setup_inputs() order:
    //  0 x, 1 edge_attr, 2 gf1, 3 bn_in_g, 4 bn_in_b,
    //  5 gat0_W, 6 gat0_asrc, 7 gat0_adst, 8 gat0_bias,
    //  9 gat_mid_W, 10 gat_mid_asrc, 11 gat_mid_adst, 12 gat_mid_bias,
    // 13 bn_mid_g, 14 bn_mid_b,
    // 15 gat_last_W, 16 gat_last_asrc, 17 gat_last_adst, 18 gat_last_bias,
    // 19 bnpool_g, 20 bnpool_b, 21 ugp1_W, 22 ugp1_b, 23 ugp2_W, 24 ugp2_b,
    // 25 dnn0_W, 26 dnn0_b, 27 dnn_mid_W, 28 dnn_mid_b, 29 dnn_last_W,
    // 30 dnn_last_b, 31 edge_index, 32 batch
    const float* gf1        = (const float*)d_in[2];
    const float* bnpool_b   = (const float*)d_in[20];
    const float* ugp1_W     = (const float*)d_in[21];
    const float* ugp1_b     = (const float*)d_in[22];
    const float* ugp2_W     = (const float*)d_in[23];
    const float* ugp2_b     = (const float*)d_in[24];
    const float* dnn0_W     = (const float*)d_in[25];
    const float* dnn0_b     = (const float*)d_in[26];
    const float* dnn_mid_W  = (const float*)d_in[27];
    const float* dnn_mid_b  = (const float*)d_in[28];
    const float* dnn_last_W = (const float*)d_in[29];
    const float* dnn_last_b = (const float*)d_in[30];
    float* out = (float*)d_out;
    float* ws  = (float*)d_ws;   // 256 B barrier counters + 800 floats

    // zero the barrier counters (stream op: graph-capture-safe, replays
    // before every kernel execution)
    hipMemsetAsync(d_ws, 0, 256, stream);

    void* args[] = {
        (void*)&gf1, (void*)&bnpool_b,
        (void*)&ugp1_W, (void*)&ugp1_b, (void*)&ugp2_W, (void*)&ugp2_b,
        (void*)&dnn0_W, (void*)&dnn0_b, (void*)&dnn_mid_W, (void*)&dnn_mid_b,
        (void*)&dnn_last_W, (void*)&dnn_last_b,
        (void*)&out, (void*)&ws
    };
    // cooperative launch: guarantees all 25 wgs co-resident (spin barrier
    // would deadlock otherwise)
    hipLaunchCooperativeKernel((void*)GATGraphModel_tail_v3,
                               dim3(NWG), dim3(BLK), args, 0, stream);
}

// Round 3
// 44.595 us; speedup vs baseline: 1.8101x; 1.0828x over previous
//
#include <hip/hip_runtime.h>
#include <math.h>

// Problem constants (from reference)
#define POOLD 50
#define GFD   45
#define DNND  400
#define ZIN   (POOLD + GFD)   // 95

// Parallel decomposition: 25 wgs x 16 output columns = 400 outputs/layer.
// t = kt*16 + tt ; tt = output lane (coalesced 64B rows), kt = 16-way K-split.
#define NWG 25
#define TT  16
#define KT  16
#define BLK (TT * KT)         // 256
#define NK  (DNND / KT)       // 25 k-iters per thread per mid layer

// Exchange buffers in ws: one per produced activation vector, sentinel-filled
// with 0xFF bytes (negative-NaN pair) each launch. Data IS the ready flag.
#define EXF   512             // floats per exchange buffer (2 KB aligned)
#define NEX   6               // dnn0 out + mid0..mid4 out (mid5 is fused)
#define SENT8 0xFFFFFFFFFFFFFFFFull
#define SENT4 0xFFFFFFFFu

__device__ __forceinline__ float elu1(float x) {
    return x > 0.f ? x : expm1f(x);
}

// The entire GNN front-end is analytically dead:
//   global_mean_pool(BatchNorm_trainstats(h)) == bnpool_b  (exactly)
// so the output reduces to a tiny MLP on constants + gf1.
// v4: 25-CU layer-parallel MLP. No barrier counters at all — consumers poll
// the 8B data slots directly (sentinel = NaN pair, unproducible by finite
// math). Weight preloads are pinned in VGPRs via empty inline-asm so their
// HBM latency hides under the poll. Final dot fused into the last layer:
// each wg publishes one partial; wg0 reduces 25 floats + sigmoid.
__global__ __launch_bounds__(BLK) void GATGraphModel_tail_v4(
    const float* __restrict__ gf1,        // [45]
    const float* __restrict__ bnpool_b,   // [14]
    const float* __restrict__ ugp1_W,     // [14,50]
    const float* __restrict__ ugp1_b,     // [50]
    const float* __restrict__ ugp2_W,     // [50,50]
    const float* __restrict__ ugp2_b,     // [50]
    const float* __restrict__ dnn0_W,     // [95,400]
    const float* __restrict__ dnn0_b,     // [400]
    const float* __restrict__ dnn_mid_W,  // [6,400,400]
    const float* __restrict__ dnn_mid_b,  // [6,400]
    const float* __restrict__ dnn_last_W, // [400,1]
    const float* __restrict__ dnn_last_b, // [1]
    float* __restrict__ out,              // [1]
    float* __restrict__ ws)               // 6*512f exchanges + 25f partials
{
    __shared__ float zs[DNND];     // staged activation vector
    __shared__ float red[BLK];     // K-split reduction scratch
    __shared__ float h2[POOLD];
    __shared__ float fin[TT];      // this wg's 16 finished outputs

    const int t     = threadIdx.x;
    const int tt    = t & (TT - 1);
    const int kt    = t >> 4;
    const int tbase = blockIdx.x * TT;

    float* finsl = ws + (size_t)NEX * EXF;   // [25] final partial sums

    // ---- preload dnn0 weight slice FIRST (overlaps the ugp dependent chain)
    float w0[6];
    #pragma unroll
    for (int j = 0; j < 6; ++j) {
        int k = kt + j * KT; if (k > ZIN - 1) k = ZIN - 1;  // clamp, predicated at use
        w0[j] = dnn0_W[k * DNND + tbase + tt];
    }
    #pragma unroll
    for (int j = 0; j < 6; ++j) asm volatile("" : "+v"(w0[j]));

    // ---- ugp chain, redundantly in every wg (13 KB of cached reads —
    // cheaper than any exchange): p0 = bnpool_b ; h2 = p0@ugp1 + b
    if (t < POOLD) {
        float acc = ugp1_b[t];
        #pragma unroll
        for (int c = 0; c < 14; ++c) acc += bnpool_b[c] * ugp1_W[c * POOLD + t];
        h2[t] = acc;
    }
    __syncthreads();
    // p = h2 @ ugp2_W + b ; z = concat(p, gf1) -> zs[0:95]
    if (t < POOLD) {
        float acc = ugp2_b[t];
        #pragma unroll 10
        for (int k = 0; k < POOLD; ++k) acc += h2[k] * ugp2_W[k * POOLD + t];
        zs[t] = acc;
    } else if (t < ZIN) {
        zs[t] = gf1[t - POOLD];
    }
    __syncthreads();

    // ---- dnn0: this wg's 16 outputs of elu(z95 @ dnn0_W + b) -> exchange 0
    {
        float acc = 0.f;
        #pragma unroll
        for (int j = 0; j < 6; ++j) {
            int k = kt + j * KT;
            if (k < ZIN) acc += zs[k] * w0[j];
        }
        red[t] = acc;
        __syncthreads();
        if (kt < 8) red[t] += red[t + 128];
        __syncthreads();
        if (kt < 4) red[t] += red[t + 64];
        __syncthreads();
        if (kt < 2) red[t] += red[t + 32];
        __syncthreads();
        if (kt == 0) {
            float v = red[t] + red[t + 16] + dnn0_b[tbase + tt];
            fin[tt] = elu1(v);
        }
        __syncthreads();
        if (t < 8) {   // publish as 8B atomic pairs (data = ready flag)
            unsigned long long v =
                ((unsigned long long)__float_as_uint(fin[2 * t + 1]) << 32) |
                (unsigned long long)__float_as_uint(fin[2 * t]);
            __hip_atomic_store((unsigned long long*)ws + (tbase >> 1) + t, v,
                               __ATOMIC_RELAXED, __HIP_MEMORY_SCOPE_AGENT);
        }
    }

    // ---- 6 mid layers: z = elu(elu(z @ W + b)); layer i reads exchange i
    for (int i = 0; i < 6; ++i) {
        const float* __restrict__ W = dnn_mid_W + (size_t)i * DNND * DNND;

        // preload this thread's 25 weight elems; pin in VGPRs so the loads
        // are in flight during the poll (v3's preload was sunk by the
        // compiler — VGPR_Count=16 proved it)
        float w[NK];
        #pragma unroll
        for (int j = 0; j < NK; ++j)
            w[j] = W[(kt + j * KT) * DNND + tbase + tt];
        #pragma unroll
        for (int j = 0; j < NK; ++j) asm volatile("" : "+v"(w[j]));

        // poll the 8B slots of exchange i directly -> zs
        const unsigned long long* s8 =
            (const unsigned long long*)(ws + (size_t)i * EXF);
        if (t < DNND / 2) {
            unsigned long long v;
            do {
                v = __hip_atomic_load(&s8[t], __ATOMIC_RELAXED,
                                      __HIP_MEMORY_SCOPE_AGENT);
            } while (v == SENT8);
            zs[2 * t]     = __uint_as_float((unsigned int)v);
            zs[2 * t + 1] = __uint_as_float((unsigned int)(v >> 32));
        }
        __syncthreads();

        float acc = 0.f;
        #pragma unroll
        for (int j = 0; j < NK; ++j) acc += zs[kt + j * KT] * w[j];
        red[t] = acc;
        __syncthreads();
        if (kt < 8) red[t] += red[t + 128];
        __syncthreads();
        if (kt < 4) red[t] += red[t + 64];
        __syncthreads();
        if (kt < 2) red[t] += red[t + 32];
        __syncthreads();
        if (kt == 0) {
            float v = red[t] + red[t + 16] + dnn_mid_b[i * DNND + tbase + tt];
            fin[tt] = elu1(elu1(v));
        }
        __syncthreads();

        if (i < 5) {
            if (t < 8) {
                unsigned long long v =
                    ((unsigned long long)__float_as_uint(fin[2 * t + 1]) << 32) |
                    (unsigned long long)__float_as_uint(fin[2 * t]);
                __hip_atomic_store(
                    (unsigned long long*)(ws + (size_t)(i + 1) * EXF) +
                        (tbase >> 1) + t,
                    v, __ATOMIC_RELAXED, __HIP_MEMORY_SCOPE_AGENT);
            }
        } else {
            // fused final dot: this wg's 16-elem partial of z @ dnn_last_W
            if (t == 0) {
                float p = 0.f;
                #pragma unroll
                for (int j = 0; j < TT; ++j) p += fin[j] * dnn_last_W[tbase + j];
                __hip_atomic_store(&finsl[blockIdx.x], p,
                                   __ATOMIC_RELAXED, __HIP_MEMORY_SCOPE_AGENT);
            }
        }
    }

    // ---- wg0: gather 25 partials, sigmoid
    if (blockIdx.x == 0) {
        if (t < NWG) {
            float v;
            do {
                v = __hip_atomic_load(&finsl[t], __ATOMIC_RELAXED,
                                      __HIP_MEMORY_SCOPE_AGENT);
            } while (__float_as_uint(v) == SENT4);
            red[t] = v;
        }
        __syncthreads();
        if (t == 0) {
            float s = dnn_last_b[0];
            for (int j = 0; j < NWG; ++j) s += red[j];
            out[0] = 1.f / (1.f + expf(-s));
        }
    }
}

extern "C" void kernel_launch(void* const* d_in, const int* in_sizes, int n_in,
                              void* d_out, int out_size, void* d_ws, size_t ws_size,
                              hipStream_t stream) {
    // setup_inputs() order:
    //  0 x, 1 edge_attr, 2 gf1, 3 bn_in_g, 4 bn_in_b,
    //  5 gat0_W, 6 gat0_asrc, 7 gat0_adst, 8 gat0_bias,
    //  9 gat_mid_W, 10 gat_mid_asrc, 11 gat_mid_adst, 12 gat_mid_bias,
    // 13 bn_mid_g, 14 bn_mid_b,
    // 15 gat_last_W, 16 gat_last_asrc, 17 gat_last_adst, 18 gat_last_bias,
    // 19 bnpool_g, 20 bnpool_b, 21 ugp1_W, 22 ugp1_b, 23 ugp2_W, 24 ugp2_b,
    // 25 dnn0_W, 26 dnn0_b, 27 dnn_mid_W, 28 dnn_mid_b, 29 dnn_last_W,
    // 30 dnn_last_b, 31 edge_index, 32 batch
    const float* gf1        = (const float*)d_in[2];
    const float* bnpool_b   = (const float*)d_in[20];
    const float* ugp1_W     = (const float*)d_in[21];
    const float* ugp1_b     = (const float*)d_in[22];
    const float* ugp2_W     = (const float*)d_in[23];
    const float* ugp2_b     = (const float*)d_in[24];
    const float* dnn0_W     = (const float*)d_in[25];
    const float* dnn0_b     = (const float*)d_in[26];
    const float* dnn_mid_W  = (const float*)d_in[27];
    const float* dnn_mid_b  = (const float*)d_in[28];
    const float* dnn_last_W = (const float*)d_in[29];
    const float* dnn_last_b = (const float*)d_in[30];
    float* out = (float*)d_out;
    float* ws  = (float*)d_ws;

    // Sentinel-fill the exchange region (6*2KB + 25*4B < 16KB) each replay.
    // 0xFF bytes = negative-NaN floats / all-ones u64: unproducible by the
    // kernel's finite arithmetic, so "slot != sentinel" means "data ready".
    hipMemsetAsync(d_ws, 0xFF, 16384, stream);

    void* args[] = {
        (void*)&gf1, (void*)&bnpool_b,
        (void*)&ugp1_W, (void*)&ugp1_b, (void*)&ugp2_W, (void*)&ugp2_b,
        (void*)&dnn0_W, (void*)&dnn0_b, (void*)&dnn_mid_W, (void*)&dnn_mid_b,
        (void*)&dnn_last_W, (void*)&dnn_last_b,
        (void*)&out, (void*)&ws
    };
    // cooperative launch: guarantees all 25 wgs co-resident (data-poll
    // would deadlock otherwise)
    hipLaunchCooperativeKernel((void*)GATGraphModel_tail_v4,
                               dim3(NWG), dim3(BLK), args, 0, stream);
}

// Round 4
// 22.787 us; speedup vs baseline: 3.5424x; 1.9571x over previous
//
#include <hip/hip_runtime.h>
#include <math.h>

// Problem constants (from reference)
#define POOLD 50
#define GFD   45
#define DNND  400
#define ZIN   (POOLD + GFD)   // 95

// Parallel decomposition: 25 wgs x 16 output columns = 400 outputs/layer.
// t = kt*16 + tt ; tt = output lane (coalesced 64B rows), kt = 16-way K-split.
#define NWG 25
#define TT  16
#define KT  16
#define BLK (TT * KT)         // 256
#define NK  (DNND / KT)       // 25 k-iters per thread per mid layer

// Exchange buffers in ws: one per produced activation vector, sentinel-filled
// with 0xFF bytes (negative-NaN pair) each launch. Data IS the ready flag.
#define EXF   512             // floats per exchange buffer (2 KB aligned)
#define NEX   6               // dnn0 out + mid0..mid4 out (mid5 is fused)
#define SENT8 0xFFFFFFFFFFFFFFFFull
#define SENT4 0xFFFFFFFFu

__device__ __forceinline__ float elu1(float x) {
    return x > 0.f ? x : expm1f(x);
}

// The entire GNN front-end is analytically dead:
//   global_mean_pool(BatchNorm_trainstats(h)) == bnpool_b  (exactly)
// so the output reduces to a tiny MLP on constants + gf1.
// v5 == v4 body (data-poll sync, no grid.sync) but launched as an ORDINARY
// kernel: cooperative launch was only providing co-residency, which 25
// blocks on a 256-CU idle device get anyway — and the coop path defeated
// hipGraph capture, costing ~40us/iteration of launch overhead (R3: our
// kernel absent from rocprof top-5 yet dur_us stuck at 44.6).
__global__ __launch_bounds__(BLK) void GATGraphModel_tail_v5(
    const float* __restrict__ gf1,        // [45]
    const float* __restrict__ bnpool_b,   // [14]
    const float* __restrict__ ugp1_W,     // [14,50]
    const float* __restrict__ ugp1_b,     // [50]
    const float* __restrict__ ugp2_W,     // [50,50]
    const float* __restrict__ ugp2_b,     // [50]
    const float* __restrict__ dnn0_W,     // [95,400]
    const float* __restrict__ dnn0_b,     // [400]
    const float* __restrict__ dnn_mid_W,  // [6,400,400]
    const float* __restrict__ dnn_mid_b,  // [6,400]
    const float* __restrict__ dnn_last_W, // [400,1]
    const float* __restrict__ dnn_last_b, // [1]
    float* __restrict__ out,              // [1]
    float* __restrict__ ws)               // 6*512f exchanges + 25f partials
{
    __shared__ float zs[DNND];     // staged activation vector
    __shared__ float red[BLK];     // K-split reduction scratch
    __shared__ float h2[POOLD];
    __shared__ float fin[TT];      // this wg's 16 finished outputs

    const int t     = threadIdx.x;
    const int tt    = t & (TT - 1);
    const int kt    = t >> 4;
    const int tbase = blockIdx.x * TT;

    float* finsl = ws + (size_t)NEX * EXF;   // [25] final partial sums

    // ---- preload dnn0 weight slice FIRST (overlaps the ugp dependent chain)
    float w0[6];
    #pragma unroll
    for (int j = 0; j < 6; ++j) {
        int k = kt + j * KT; if (k > ZIN - 1) k = ZIN - 1;  // clamp, predicated at use
        w0[j] = dnn0_W[k * DNND + tbase + tt];
    }
    #pragma unroll
    for (int j = 0; j < 6; ++j) asm volatile("" : "+v"(w0[j]));

    // ---- ugp chain, redundantly in every wg (13 KB of cached reads —
    // cheaper than any exchange): p0 = bnpool_b ; h2 = p0@ugp1 + b
    if (t < POOLD) {
        float acc = ugp1_b[t];
        #pragma unroll
        for (int c = 0; c < 14; ++c) acc += bnpool_b[c] * ugp1_W[c * POOLD + t];
        h2[t] = acc;
    }
    __syncthreads();
    // p = h2 @ ugp2_W + b ; z = concat(p, gf1) -> zs[0:95]
    if (t < POOLD) {
        float acc = ugp2_b[t];
        #pragma unroll 10
        for (int k = 0; k < POOLD; ++k) acc += h2[k] * ugp2_W[k * POOLD + t];
        zs[t] = acc;
    } else if (t < ZIN) {
        zs[t] = gf1[t - POOLD];
    }
    __syncthreads();

    // ---- dnn0: this wg's 16 outputs of elu(z95 @ dnn0_W + b) -> exchange 0
    {
        float acc = 0.f;
        #pragma unroll
        for (int j = 0; j < 6; ++j) {
            int k = kt + j * KT;
            if (k < ZIN) acc += zs[k] * w0[j];
        }
        red[t] = acc;
        __syncthreads();
        if (kt < 8) red[t] += red[t + 128];
        __syncthreads();
        if (kt < 4) red[t] += red[t + 64];
        __syncthreads();
        if (kt < 2) red[t] += red[t + 32];
        __syncthreads();
        if (kt == 0) {
            float v = red[t] + red[t + 16] + dnn0_b[tbase + tt];
            fin[tt] = elu1(v);
        }
        __syncthreads();
        if (t < 8) {   // publish as 8B atomic pairs (data = ready flag)
            unsigned long long v =
                ((unsigned long long)__float_as_uint(fin[2 * t + 1]) << 32) |
                (unsigned long long)__float_as_uint(fin[2 * t]);
            __hip_atomic_store((unsigned long long*)ws + (tbase >> 1) + t, v,
                               __ATOMIC_RELAXED, __HIP_MEMORY_SCOPE_AGENT);
        }
    }

    // ---- 6 mid layers: z = elu(elu(z @ W + b)); layer i reads exchange i
    for (int i = 0; i < 6; ++i) {
        const float* __restrict__ W = dnn_mid_W + (size_t)i * DNND * DNND;

        // preload this thread's 25 weight elems; pin in VGPRs so the loads
        // are in flight during the poll (v3's preload was sunk by the
        // compiler — VGPR_Count=16 proved it)
        float w[NK];
        #pragma unroll
        for (int j = 0; j < NK; ++j)
            w[j] = W[(kt + j * KT) * DNND + tbase + tt];
        #pragma unroll
        for (int j = 0; j < NK; ++j) asm volatile("" : "+v"(w[j]));

        // poll the 8B slots of exchange i directly -> zs
        const unsigned long long* s8 =
            (const unsigned long long*)(ws + (size_t)i * EXF);
        if (t < DNND / 2) {
            unsigned long long v;
            do {
                v = __hip_atomic_load(&s8[t], __ATOMIC_RELAXED,
                                      __HIP_MEMORY_SCOPE_AGENT);
            } while (v == SENT8);
            zs[2 * t]     = __uint_as_float((unsigned int)v);
            zs[2 * t + 1] = __uint_as_float((unsigned int)(v >> 32));
        }
        __syncthreads();

        float acc = 0.f;
        #pragma unroll
        for (int j = 0; j < NK; ++j) acc += zs[kt + j * KT] * w[j];
        red[t] = acc;
        __syncthreads();
        if (kt < 8) red[t] += red[t + 128];
        __syncthreads();
        if (kt < 4) red[t] += red[t + 64];
        __syncthreads();
        if (kt < 2) red[t] += red[t + 32];
        __syncthreads();
        if (kt == 0) {
            float v = red[t] + red[t + 16] + dnn_mid_b[i * DNND + tbase + tt];
            fin[tt] = elu1(elu1(v));
        }
        __syncthreads();

        if (i < 5) {
            if (t < 8) {
                unsigned long long v =
                    ((unsigned long long)__float_as_uint(fin[2 * t + 1]) << 32) |
                    (unsigned long long)__float_as_uint(fin[2 * t]);
                __hip_atomic_store(
                    (unsigned long long*)(ws + (size_t)(i + 1) * EXF) +
                        (tbase >> 1) + t,
                    v, __ATOMIC_RELAXED, __HIP_MEMORY_SCOPE_AGENT);
            }
        } else {
            // fused final dot: this wg's 16-elem partial of z @ dnn_last_W
            if (t == 0) {
                float p = 0.f;
                #pragma unroll
                for (int j = 0; j < TT; ++j) p += fin[j] * dnn_last_W[tbase + j];
                __hip_atomic_store(&finsl[blockIdx.x], p,
                                   __ATOMIC_RELAXED, __HIP_MEMORY_SCOPE_AGENT);
            }
        }
    }

    // ---- wg0: gather 25 partials, sigmoid
    if (blockIdx.x == 0) {
        if (t < NWG) {
            float v;
            do {
                v = __hip_atomic_load(&finsl[t], __ATOMIC_RELAXED,
                                      __HIP_MEMORY_SCOPE_AGENT);
            } while (__float_as_uint(v) == SENT4);
            red[t] = v;
        }
        __syncthreads();
        if (t == 0) {
            float s = dnn_last_b[0];
            for (int j = 0; j < NWG; ++j) s += red[j];
            out[0] = 1.f / (1.f + expf(-s));
        }
    }
}

extern "C" void kernel_launch(void* const* d_in, const int* in_sizes, int n_in,
                              void* d_out, int out_size, void* d_ws, size_t ws_size,
                              hipStream_t stream) {
    // setup_inputs() order:
    //  0 x, 1 edge_attr, 2 gf1, 3 bn_in_g, 4 bn_in_b,
    //  5 gat0_W, 6 gat0_asrc, 7 gat0_adst, 8 gat0_bias,
    //  9 gat_mid_W, 10 gat_mid_asrc, 11 gat_mid_adst, 12 gat_mid_bias,
    // 13 bn_mid_g, 14 bn_mid_b,
    // 15 gat_last_W, 16 gat_last_asrc, 17 gat_last_adst, 18 gat_last_bias,
    // 19 bnpool_g, 20 bnpool_b, 21 ugp1_W, 22 ugp1_b, 23 ugp2_W, 24 ugp2_b,
    // 25 dnn0_W, 26 dnn0_b, 27 dnn_mid_W, 28 dnn_mid_b, 29 dnn_last_W,
    // 30 dnn_last_b, 31 edge_index, 32 batch
    const float* gf1        = (const float*)d_in[2];
    const float* bnpool_b   = (const float*)d_in[20];
    const float* ugp1_W     = (const float*)d_in[21];
    const float* ugp1_b     = (const float*)d_in[22];
    const float* ugp2_W     = (const float*)d_in[23];
    const float* ugp2_b     = (const float*)d_in[24];
    const float* dnn0_W     = (const float*)d_in[25];
    const float* dnn0_b     = (const float*)d_in[26];
    const float* dnn_mid_W  = (const float*)d_in[27];
    const float* dnn_mid_b  = (const float*)d_in[28];
    const float* dnn_last_W = (const float*)d_in[29];
    const float* dnn_last_b = (const float*)d_in[30];
    float* out = (float*)d_out;
    float* ws  = (float*)d_ws;

    // Sentinel-fill the exchange region (6*2KB + 25*4B < 16KB) each replay.
    // 0xFF bytes = negative-NaN floats / all-ones u64: unproducible by the
    // kernel's finite arithmetic, so "slot != sentinel" means "data ready".
    hipMemsetAsync(d_ws, 0xFF, 16384, stream);

    // ORDINARY launch (graph-capturable). Co-residency of all 25 blocks is
    // guaranteed in practice: grid (25) << CU count (256), trivial VGPR/LDS.
    hipLaunchKernelGGL(GATGraphModel_tail_v5, dim3(NWG), dim3(BLK), 0, stream,
                       gf1, bnpool_b, ugp1_W, ugp1_b, ugp2_W, ugp2_b,
                       dnn0_W, dnn0_b, dnn_mid_W, dnn_mid_b,
                       dnn_last_W, dnn_last_b, out, ws);
}